// Round 4
// baseline (434.842 us; speedup 1.0000x reference)
//
#include <hip/hip_runtime.h>

#define BATCH   8192
#define FPP     32
#define FT_OUT  1024
#define N_VFEAT 768
#define N_FEAT  49152

#define WQ_BYTES   ((size_t)N_FEAT * FT_OUT)              // 50,331,648 int8
#define WS_NEEDED  (WQ_BYTES + (size_t)N_FEAT * 4)        // + per-row scales

typedef signed char c16 __attribute__((ext_vector_type(16)));
typedef float       f4  __attribute__((ext_vector_type(4)));   // native vec for nontemporal builtins

// ---------- build combined int8 table: Wc[f] = W_ft[f] + W_fft[f % 768] ----------
// One WAVE per feature row (4 rows / 256-thread block). No __syncthreads, no LDS:
// 64-lane shfl_xor max-reduction. Fully coalesced dwordx4 loads (1 KB/wave-instr).
__global__ __launch_bounds__(256) void build_combined_i8(
    const float* __restrict__ W_ft,
    const float* __restrict__ W_fft,
    signed char* __restrict__ Wq,
    float*       __restrict__ scales)
{
    const int wave = threadIdx.x >> 6;            // 0..3
    const int lane = threadIdx.x & 63;
    const int f    = blockIdx.x * 4 + wave;
    // f % 768: 768 = 4*192, so (bx % 192)*4 + wave
    const int fm   = (blockIdx.x % (N_VFEAT / 4)) * 4 + wave;

    const float* a = W_ft  + (size_t)f  * FT_OUT;
    const float* g = W_fft + (size_t)fm * FT_OUT;

    float c[16];
#pragma unroll
    for (int ch = 0; ch < 4; ++ch) {
        // W_ft: streamed once -> non-temporal (keep L2 for Wq + W_fft)
        const f4 av = __builtin_nontemporal_load(
            reinterpret_cast<const f4*>(a + ch * 256 + lane * 4));
        const f4 gv = *reinterpret_cast<const f4*>(g + ch * 256 + lane * 4);
        c[ch * 4 + 0] = av.x + gv.x;
        c[ch * 4 + 1] = av.y + gv.y;
        c[ch * 4 + 2] = av.z + gv.z;
        c[ch * 4 + 3] = av.w + gv.w;
    }

    float m = 0.0f;
#pragma unroll
    for (int j = 0; j < 16; ++j) m = fmaxf(m, fabsf(c[j]));
#pragma unroll
    for (int o = 32; o > 0; o >>= 1)
        m = fmaxf(m, __shfl_xor(m, o, 64));      // all lanes hold row max

    const float am  = fmaxf(m, 1e-20f);
    const float inv = 127.0f / am;
    if (lane == 0) scales[f] = am / 127.0f;

#pragma unroll
    for (int ch = 0; ch < 4; ++ch) {
        int q0 = (int)rintf(c[ch * 4 + 0] * inv);
        int q1 = (int)rintf(c[ch * 4 + 1] * inv);
        int q2 = (int)rintf(c[ch * 4 + 2] * inv);
        int q3 = (int)rintf(c[ch * 4 + 3] * inv);
        q0 = max(-127, min(127, q0));
        q1 = max(-127, min(127, q1));
        q2 = max(-127, min(127, q2));
        q3 = max(-127, min(127, q3));
        char4 pk;
        pk.x = (signed char)q0; pk.y = (signed char)q1;
        pk.z = (signed char)q2; pk.w = (signed char)q3;
        *reinterpret_cast<char4*>(Wq + (size_t)f * FT_OUT + ch * 256 + lane * 4) = pk;
    }
}

// ---------- main gather kernel ----------
// 2 batch rows per 256-thread block; one WAVE per (batch, side).
// Each lane owns 16 contiguous cols -> one c16 (16 B) load fetches a whole
// 1 KB row per wave instruction.
__global__ __launch_bounds__(256) void nnue_fwd_i8(
    const float*       __restrict__ values,
    const int*         __restrict__ stm_feat,
    const int*         __restrict__ nstm_feat,
    const signed char* __restrict__ Wq,
    const float*       __restrict__ scales,
    const float*       __restrict__ b_ft,
    const float*       __restrict__ b_fft,
    const float*       __restrict__ W_out,
    const float*       __restrict__ b_out,
    float*             __restrict__ out)
{
    const int tid  = threadIdx.x;
    const int wave = tid >> 6;          // 0..3
    const int lane = tid & 63;
    const int bl   = wave >> 1;         // batch slot within block (0..1)
    const int sd   = wave & 1;          // 0 = stm, 1 = nstm
    const int c0   = lane * 16;

    __shared__ int   s_off[2][2][FPP];  // [batch][side][k] -> elem offset of row
    __shared__ float s_vs [2][2][FPP];  // value * row_scale
    __shared__ float s_red[2][2];

    if (tid < 128) {
        const int lb = tid >> 6;                       // batch slot
        const int ls = (tid >> 5) & 1;                 // side
        const int k  = tid & 31;
        const int b  = blockIdx.x * 2 + lb;
        const int f  = (ls ? nstm_feat : stm_feat)[b * FPP + k];
        s_off[lb][ls][k] = f * FT_OUT;
        s_vs [lb][ls][k] = values[b * FPP + k] * scales[f];
    }
    __syncthreads();

    float acc[16];
#pragma unroll
    for (int j = 0; j < 16; ++j) acc[j] = 0.0f;

#pragma unroll 8
    for (int k = 0; k < FPP; ++k) {
        const c16 q = *reinterpret_cast<const c16*>(Wq + s_off[bl][sd][k] + c0);
        const float vs = s_vs[bl][sd][k];
#pragma unroll
        for (int j = 0; j < 16; ++j)
            acc[j] += vs * (float)q[j];
    }

    float partial = 0.0f;
#pragma unroll
    for (int ch = 0; ch < 4; ++ch) {
        const float4 bf = *reinterpret_cast<const float4*>(b_ft  + c0 + 4 * ch);
        const float4 bg = *reinterpret_cast<const float4*>(b_fft + c0 + 4 * ch);
        const float4 wo = *reinterpret_cast<const float4*>(W_out + sd * FT_OUT + c0 + 4 * ch);
        float h;
        h = acc[ch * 4 + 0] + bf.x + bg.x; h = fminf(fmaxf(h, 0.0f), 1.0f); partial += h * wo.x;
        h = acc[ch * 4 + 1] + bf.y + bg.y; h = fminf(fmaxf(h, 0.0f), 1.0f); partial += h * wo.y;
        h = acc[ch * 4 + 2] + bf.z + bg.z; h = fminf(fmaxf(h, 0.0f), 1.0f); partial += h * wo.z;
        h = acc[ch * 4 + 3] + bf.w + bg.w; h = fminf(fmaxf(h, 0.0f), 1.0f); partial += h * wo.w;
    }

#pragma unroll
    for (int o = 32; o > 0; o >>= 1)
        partial += __shfl_down(partial, o, 64);

    if (lane == 0) s_red[bl][sd] = partial;
    __syncthreads();

    if (tid < 2) {
        float x = s_red[tid][0] + s_red[tid][1] + b_out[0];
        out[blockIdx.x * 2 + tid] = 1.0f / (1.0f + __expf(-x));
    }
}

// ---------- fp32 fallback (used only if ws_size too small) ----------
__global__ __launch_bounds__(256) void nnue_fwd_f32(
    const float* __restrict__ values,
    const int*   __restrict__ stm_feat,
    const int*   __restrict__ nstm_feat,
    const float* __restrict__ W_ft,
    const float* __restrict__ b_ft,
    const float* __restrict__ W_fft,
    const float* __restrict__ b_fft,
    const float* __restrict__ W_out,
    const float* __restrict__ b_out,
    float*       __restrict__ out)
{
    const int b    = blockIdx.x;
    const int tid  = threadIdx.x;
    const int side = tid >> 7;
    const int lane = tid & 127;
    const int c0   = lane * 8;

    __shared__ int   s_off_ft [2][FPP];
    __shared__ int   s_off_fft[2][FPP];
    __shared__ float s_val[FPP];
    __shared__ float s_red[4];

    if (tid < FPP) {
        int f = stm_feat[b * FPP + tid];
        s_off_ft [0][tid] = f * FT_OUT;
        s_off_fft[0][tid] = (f % N_VFEAT) * FT_OUT;
        s_val[tid] = values[b * FPP + tid];
    } else if (tid < 2 * FPP) {
        int k = tid - FPP;
        int f = nstm_feat[b * FPP + k];
        s_off_ft [1][k] = f * FT_OUT;
        s_off_fft[1][k] = (f % N_VFEAT) * FT_OUT;
    }
    __syncthreads();

    float acc[8];
#pragma unroll
    for (int j = 0; j < 8; ++j) acc[j] = 0.0f;

#pragma unroll 4
    for (int k = 0; k < FPP; ++k) {
        const float* ra = W_ft  + s_off_ft [side][k] + c0;
        const float* rg = W_fft + s_off_fft[side][k] + c0;
        const float4 a0 = *reinterpret_cast<const float4*>(ra);
        const float4 a1 = *reinterpret_cast<const float4*>(ra + 4);
        const float4 g0 = *reinterpret_cast<const float4*>(rg);
        const float4 g1 = *reinterpret_cast<const float4*>(rg + 4);
        const float v = s_val[k];
        acc[0] += (a0.x + g0.x) * v;  acc[1] += (a0.y + g0.y) * v;
        acc[2] += (a0.z + g0.z) * v;  acc[3] += (a0.w + g0.w) * v;
        acc[4] += (a1.x + g1.x) * v;  acc[5] += (a1.y + g1.y) * v;
        acc[6] += (a1.z + g1.z) * v;  acc[7] += (a1.w + g1.w) * v;
    }

    float partial = 0.0f;
#pragma unroll
    for (int j = 0; j < 8; ++j) {
        float h = acc[j] + b_ft[c0 + j] + b_fft[c0 + j];
        h = fminf(fmaxf(h, 0.0f), 1.0f);
        partial += h * W_out[side * FT_OUT + c0 + j];
    }
#pragma unroll
    for (int o = 32; o > 0; o >>= 1)
        partial += __shfl_down(partial, o, 64);
    const int wv = tid >> 6;
    if ((tid & 63) == 0) s_red[wv] = partial;
    __syncthreads();
    if (tid == 0) {
        float x = s_red[0] + s_red[1] + s_red[2] + s_red[3] + b_out[0];
        out[b] = 1.0f / (1.0f + __expf(-x));
    }
}

extern "C" void kernel_launch(void* const* d_in, const int* in_sizes, int n_in,
                              void* d_out, int out_size, void* d_ws, size_t ws_size,
                              hipStream_t stream) {
    const float* values    = (const float*)d_in[0];
    const int*   stm_feat  = (const int*)d_in[1];
    const int*   nstm_feat = (const int*)d_in[2];
    // d_in[3] = batch_idx: structurally repeat(arange(B), FPP) -> nnz n maps to batch n>>5
    const float* W_ft      = (const float*)d_in[4];
    const float* b_ft      = (const float*)d_in[5];
    const float* W_fft     = (const float*)d_in[6];
    const float* b_fft     = (const float*)d_in[7];
    const float* W_out     = (const float*)d_in[8];
    const float* b_out     = (const float*)d_in[9];
    float*       out       = (float*)d_out;

    if (ws_size >= WS_NEEDED) {
        signed char* Wq     = (signed char*)d_ws;
        float*       scales = (float*)((char*)d_ws + WQ_BYTES);

        build_combined_i8<<<N_FEAT / 4, 256, 0, stream>>>(W_ft, W_fft, Wq, scales);

        // MEASUREMENT ROUND: launch the gather TWICE (idempotent — second run
        // rewrites identical values to out). dur_us = fills + B + 2G = 359 + G,
        // which pins down the per-kernel split that top-5 counters hide.
        nnue_fwd_i8<<<BATCH / 2, 256, 0, stream>>>(
            values, stm_feat, nstm_feat, Wq, scales, b_ft, b_fft, W_out, b_out, out);
        nnue_fwd_i8<<<BATCH / 2, 256, 0, stream>>>(
            values, stm_feat, nstm_feat, Wq, scales, b_ft, b_fft, W_out, b_out, out);
    } else {
        nnue_fwd_f32<<<BATCH, 256, 0, stream>>>(
            values, stm_feat, nstm_feat, W_ft, b_ft, W_fft, b_fft, W_out, b_out, out);
    }
}

// Round 5
// 358.562 us; speedup vs baseline: 1.2127x; 1.2127x over previous
//
#include <hip/hip_runtime.h>

#define BATCH   8192
#define FPP     32
#define FT_OUT  1024
#define N_VFEAT 768
#define N_FEAT  49152

#define WQ_BYTES   ((size_t)N_FEAT * FT_OUT)              // 50,331,648 bytes
#define WS_NEEDED  (WQ_BYTES + (size_t)N_FEAT * 4)        // + per-row scales

typedef float f4 __attribute__((ext_vector_type(4)));     // native vec for nontemporal builtins
typedef short s2 __attribute__((ext_vector_type(2)));

// v_dot2_i32_i16: D = S0.i16[0]*S1.i16[0] + S0.i16[1]*S1.i16[1] + S2
static __device__ __forceinline__ int sdot2(int a, int b, int c) {
#if __has_builtin(__builtin_amdgcn_sdot2)
    return __builtin_amdgcn_sdot2(__builtin_bit_cast(s2, a), __builtin_bit_cast(s2, b), c, false);
#else
    int d;
    asm volatile("v_dot2_i32_i16 %0, %1, %2, %3" : "=v"(d) : "v"(a), "v"(b), "v"(c));
    return d;
#endif
}

// ---------- build combined BIASED-u8 table: Wc[f] = W_ft[f] + W_fft[f % 768] ----------
// Stored value u = round(127*c/rowmax) + 128  (u in [1,255]).
// One WAVE per feature row (4 rows / 256-thread block), shfl-only reduction.
__global__ __launch_bounds__(256) void build_combined_i8(
    const float* __restrict__ W_ft,
    const float* __restrict__ W_fft,
    unsigned char* __restrict__ Wq,
    float*       __restrict__ scales)
{
    const int wave = threadIdx.x >> 6;            // 0..3
    const int lane = threadIdx.x & 63;
    const int f    = blockIdx.x * 4 + wave;
    const int fm   = (blockIdx.x % (N_VFEAT / 4)) * 4 + wave;   // f % 768

    const float* a = W_ft  + (size_t)f  * FT_OUT;
    const float* g = W_fft + (size_t)fm * FT_OUT;

    float c[16];
#pragma unroll
    for (int ch = 0; ch < 4; ++ch) {
        const f4 av = __builtin_nontemporal_load(
            reinterpret_cast<const f4*>(a + ch * 256 + lane * 4));
        const f4 gv = *reinterpret_cast<const f4*>(g + ch * 256 + lane * 4);
        c[ch * 4 + 0] = av.x + gv.x;
        c[ch * 4 + 1] = av.y + gv.y;
        c[ch * 4 + 2] = av.z + gv.z;
        c[ch * 4 + 3] = av.w + gv.w;
    }

    float m = 0.0f;
#pragma unroll
    for (int j = 0; j < 16; ++j) m = fmaxf(m, fabsf(c[j]));
#pragma unroll
    for (int o = 32; o > 0; o >>= 1)
        m = fmaxf(m, __shfl_xor(m, o, 64));      // all lanes hold row max

    const float am  = fmaxf(m, 1e-20f);
    const float inv = 127.0f / am;
    if (lane == 0) scales[f] = am / 127.0f;

#pragma unroll
    for (int ch = 0; ch < 4; ++ch) {
        int q0 = (int)rintf(c[ch * 4 + 0] * inv);
        int q1 = (int)rintf(c[ch * 4 + 1] * inv);
        int q2 = (int)rintf(c[ch * 4 + 2] * inv);
        int q3 = (int)rintf(c[ch * 4 + 3] * inv);
        q0 = max(-127, min(127, q0)) + 128;
        q1 = max(-127, min(127, q1)) + 128;
        q2 = max(-127, min(127, q2)) + 128;
        q3 = max(-127, min(127, q3)) + 128;
        uchar4 pk;
        pk.x = (unsigned char)q0; pk.y = (unsigned char)q1;
        pk.z = (unsigned char)q2; pk.w = (unsigned char)q3;
        *reinterpret_cast<uchar4*>(Wq + (size_t)f * FT_OUT + ch * 256 + lane * 4) = pk;
    }
}

// ---------- main gather kernel: integer dot2 inner loop ----------
// 2 batch rows per 256-thread block; one WAVE per (batch, side); 16 cols/lane.
// Per k-pair: 2x 16B row loads; per 2 elements: 1 v_perm_b32 + 1 v_dot2_i32_i16.
// acc[j] = sigma * (SUM_k t_k*u_kj - 128*SUM_k t_k), exact in int32.
__global__ __launch_bounds__(256) void nnue_fwd_i8(
    const float*         __restrict__ values,
    const int*           __restrict__ stm_feat,
    const int*           __restrict__ nstm_feat,
    const unsigned char* __restrict__ Wq,
    const float*         __restrict__ scales,
    const float*         __restrict__ b_ft,
    const float*         __restrict__ b_fft,
    const float*         __restrict__ W_out,
    const float*         __restrict__ b_out,
    float*               __restrict__ out)
{
    const int tid  = threadIdx.x;
    const int wave = tid >> 6;          // 0..3
    const int lane = tid & 63;
    const int bl   = wave >> 1;         // batch slot within block (0..1)
    const int sd   = wave & 1;          // 0 = stm, 1 = nstm
    const int c0   = lane * 16;

    __shared__ int   s_off [2][2][FPP];      // row elem offsets
    __shared__ int   s_tp  [2][2][FPP / 2];  // packed {t_2k, t_2k+1} as i16x2
    __shared__ float s_sig [2][2];           // sigma = vmax/32767
    __shared__ int   s_tsum[2][2];           // SUM t_k
    __shared__ float s_red [2][2];

    if (tid < 128) {
        const int g  = tid >> 5;                       // (batch,side) group 0..3
        const int lb = g >> 1;
        const int ls = g & 1;
        const int k  = tid & 31;
        const int b  = blockIdx.x * 2 + lb;
        const int f  = (ls ? nstm_feat : stm_feat)[b * FPP + k];
        s_off[lb][ls][k] = f * FT_OUT;
        const float vs = values[b * FPP + k] * scales[f];

        float vmax = fabsf(vs);
#pragma unroll
        for (int o = 16; o > 0; o >>= 1)
            vmax = fmaxf(vmax, __shfl_xor(vmax, o, 32));
        vmax = fmaxf(vmax, 1e-30f);

        const int t = (int)rintf(vs * (32767.0f / vmax));
        int tsum = t;
#pragma unroll
        for (int o = 16; o > 0; o >>= 1)
            tsum += __shfl_xor(tsum, o, 32);
        const int tnext = __shfl_down(t, 1, 32);
        if ((k & 1) == 0)
            s_tp[lb][ls][k >> 1] = (t & 0xffff) | (tnext << 16);
        if (k == 0) {
            s_sig [lb][ls] = vmax / 32767.0f;
            s_tsum[lb][ls] = tsum;
        }
    }
    __syncthreads();

    int acci[16];
#pragma unroll
    for (int j = 0; j < 16; ++j) acci[j] = 0;

    // sel for byte j: {0x0C(=0), j(from S1=qb), 0x0C(=0), 4+j(from S0=qa)}
    //   -> dword { hi16 = u_b (row 2k+1), lo16 = u_a (row 2k) }, zero-extended.
#define DOT_STEP(d, av, bv)                                                          \
    acci[4*(d)+0] = sdot2(tp, (int)__builtin_amdgcn_perm((av), (bv), 0x0C000C04u), acci[4*(d)+0]); \
    acci[4*(d)+1] = sdot2(tp, (int)__builtin_amdgcn_perm((av), (bv), 0x0C010C05u), acci[4*(d)+1]); \
    acci[4*(d)+2] = sdot2(tp, (int)__builtin_amdgcn_perm((av), (bv), 0x0C020C06u), acci[4*(d)+2]); \
    acci[4*(d)+3] = sdot2(tp, (int)__builtin_amdgcn_perm((av), (bv), 0x0C030C07u), acci[4*(d)+3]);

#pragma unroll 4
    for (int kp = 0; kp < FPP / 2; ++kp) {
        const uint4 qa = *reinterpret_cast<const uint4*>(Wq + s_off[bl][sd][2 * kp]     + c0);
        const uint4 qb = *reinterpret_cast<const uint4*>(Wq + s_off[bl][sd][2 * kp + 1] + c0);
        const int tp = s_tp[bl][sd][kp];
        DOT_STEP(0, qa.x, qb.x)
        DOT_STEP(1, qa.y, qb.y)
        DOT_STEP(2, qa.z, qb.z)
        DOT_STEP(3, qa.w, qb.w)
    }
#undef DOT_STEP

    const float sigma = s_sig [bl][sd];
    const int   tsum  = s_tsum[bl][sd];
    const int   corr  = 128 * tsum;

    float partial = 0.0f;
#pragma unroll
    for (int ch = 0; ch < 4; ++ch) {
        const float4 bf = *reinterpret_cast<const float4*>(b_ft  + c0 + 4 * ch);
        const float4 bg = *reinterpret_cast<const float4*>(b_fft + c0 + 4 * ch);
        const float4 wo = *reinterpret_cast<const float4*>(W_out + sd * FT_OUT + c0 + 4 * ch);
        float h;
        h = sigma * (float)(acci[ch * 4 + 0] - corr) + bf.x + bg.x;
        h = fminf(fmaxf(h, 0.0f), 1.0f); partial += h * wo.x;
        h = sigma * (float)(acci[ch * 4 + 1] - corr) + bf.y + bg.y;
        h = fminf(fmaxf(h, 0.0f), 1.0f); partial += h * wo.y;
        h = sigma * (float)(acci[ch * 4 + 2] - corr) + bf.z + bg.z;
        h = fminf(fmaxf(h, 0.0f), 1.0f); partial += h * wo.z;
        h = sigma * (float)(acci[ch * 4 + 3] - corr) + bf.w + bg.w;
        h = fminf(fmaxf(h, 0.0f), 1.0f); partial += h * wo.w;
    }

#pragma unroll
    for (int o = 32; o > 0; o >>= 1)
        partial += __shfl_down(partial, o, 64);

    if (lane == 0) s_red[bl][sd] = partial;
    __syncthreads();

    if (tid < 2) {
        float x = s_red[tid][0] + s_red[tid][1] + b_out[0];
        out[blockIdx.x * 2 + tid] = 1.0f / (1.0f + __expf(-x));
    }
}

// ---------- fp32 fallback (used only if ws_size too small) ----------
__global__ __launch_bounds__(256) void nnue_fwd_f32(
    const float* __restrict__ values,
    const int*   __restrict__ stm_feat,
    const int*   __restrict__ nstm_feat,
    const float* __restrict__ W_ft,
    const float* __restrict__ b_ft,
    const float* __restrict__ W_fft,
    const float* __restrict__ b_fft,
    const float* __restrict__ W_out,
    const float* __restrict__ b_out,
    float*       __restrict__ out)
{
    const int b    = blockIdx.x;
    const int tid  = threadIdx.x;
    const int side = tid >> 7;
    const int lane = tid & 127;
    const int c0   = lane * 8;

    __shared__ int   s_off_ft [2][FPP];
    __shared__ int   s_off_fft[2][FPP];
    __shared__ float s_val[FPP];
    __shared__ float s_red[4];

    if (tid < FPP) {
        int f = stm_feat[b * FPP + tid];
        s_off_ft [0][tid] = f * FT_OUT;
        s_off_fft[0][tid] = (f % N_VFEAT) * FT_OUT;
        s_val[tid] = values[b * FPP + tid];
    } else if (tid < 2 * FPP) {
        int k = tid - FPP;
        int f = nstm_feat[b * FPP + k];
        s_off_ft [1][k] = f * FT_OUT;
        s_off_fft[1][k] = (f % N_VFEAT) * FT_OUT;
    }
    __syncthreads();

    float acc[8];
#pragma unroll
    for (int j = 0; j < 8; ++j) acc[j] = 0.0f;

#pragma unroll 4
    for (int k = 0; k < FPP; ++k) {
        const float* ra = W_ft  + s_off_ft [side][k] + c0;
        const float* rg = W_fft + s_off_fft[side][k] + c0;
        const float4 a0 = *reinterpret_cast<const float4*>(ra);
        const float4 a1 = *reinterpret_cast<const float4*>(ra + 4);
        const float4 g0 = *reinterpret_cast<const float4*>(rg);
        const float4 g1 = *reinterpret_cast<const float4*>(rg + 4);
        const float v = s_val[k];
        acc[0] += (a0.x + g0.x) * v;  acc[1] += (a0.y + g0.y) * v;
        acc[2] += (a0.z + g0.z) * v;  acc[3] += (a0.w + g0.w) * v;
        acc[4] += (a1.x + g1.x) * v;  acc[5] += (a1.y + g1.y) * v;
        acc[6] += (a1.z + g1.z) * v;  acc[7] += (a1.w + g1.w) * v;
    }

    float partial = 0.0f;
#pragma unroll
    for (int j = 0; j < 8; ++j) {
        float h = acc[j] + b_ft[c0 + j] + b_fft[c0 + j];
        h = fminf(fmaxf(h, 0.0f), 1.0f);
        partial += h * W_out[side * FT_OUT + c0 + j];
    }
#pragma unroll
    for (int o = 32; o > 0; o >>= 1)
        partial += __shfl_down(partial, o, 64);
    const int wv = tid >> 6;
    if ((tid & 63) == 0) s_red[wv] = partial;
    __syncthreads();
    if (tid == 0) {
        float x = s_red[0] + s_red[1] + s_red[2] + s_red[3] + b_out[0];
        out[b] = 1.0f / (1.0f + __expf(-x));
    }
}

extern "C" void kernel_launch(void* const* d_in, const int* in_sizes, int n_in,
                              void* d_out, int out_size, void* d_ws, size_t ws_size,
                              hipStream_t stream) {
    const float* values    = (const float*)d_in[0];
    const int*   stm_feat  = (const int*)d_in[1];
    const int*   nstm_feat = (const int*)d_in[2];
    // d_in[3] = batch_idx: structurally repeat(arange(B), FPP) -> nnz n maps to batch n>>5
    const float* W_ft      = (const float*)d_in[4];
    const float* b_ft      = (const float*)d_in[5];
    const float* W_fft     = (const float*)d_in[6];
    const float* b_fft     = (const float*)d_in[7];
    const float* W_out     = (const float*)d_in[8];
    const float* b_out     = (const float*)d_in[9];
    float*       out       = (float*)d_out;

    if (ws_size >= WS_NEEDED) {
        unsigned char* Wq     = (unsigned char*)d_ws;
        float*         scales = (float*)((char*)d_ws + WQ_BYTES);

        build_combined_i8<<<N_FEAT / 4, 256, 0, stream>>>(W_ft, W_fft, Wq, scales);

        nnue_fwd_i8<<<BATCH / 2, 256, 0, stream>>>(
            values, stm_feat, nstm_feat, Wq, scales, b_ft, b_fft, W_out, b_out, out);
    } else {
        nnue_fwd_f32<<<BATCH, 256, 0, stream>>>(
            values, stm_feat, nstm_feat, W_ft, b_ft, W_fft, b_fft, W_out, b_out, out);
    }
}

// Round 6
// 356.208 us; speedup vs baseline: 1.2208x; 1.0066x over previous
//
#include <hip/hip_runtime.h>

#define BATCH   8192
#define FPP     32
#define FT_OUT  1024
#define N_VFEAT 768
#define N_FEAT  49152

#define WQ_BYTES   ((size_t)N_FEAT * FT_OUT)              // 50,331,648 bytes
#define WS_NEEDED  (WQ_BYTES + (size_t)N_FEAT * 4)        // + per-row scales

typedef float f4 __attribute__((ext_vector_type(4)));     // native vec for nontemporal builtins
typedef short s2 __attribute__((ext_vector_type(2)));

// v_dot2_i32_i16: D = S0.i16[0]*S1.i16[0] + S0.i16[1]*S1.i16[1] + S2
static __device__ __forceinline__ int sdot2(int a, int b, int c) {
#if __has_builtin(__builtin_amdgcn_sdot2)
    return __builtin_amdgcn_sdot2(__builtin_bit_cast(s2, a), __builtin_bit_cast(s2, b), c, false);
#else
    int d;
    asm volatile("v_dot2_i32_i16 %0, %1, %2, %3" : "=v"(d) : "v"(a), "v"(b), "v"(c));
    return d;
#endif
}

// ---------- build combined BIASED-u8 table: Wc[f] = W_ft[f] + W_fft[f % 768] ----------
// Stored value u = round(127*c/rowmax) + 128  (u in [1,255]).
// One WAVE per feature row (4 rows / 256-thread block), shfl-only reduction.
__global__ __launch_bounds__(256) void build_combined_i8(
    const float* __restrict__ W_ft,
    const float* __restrict__ W_fft,
    unsigned char* __restrict__ Wq,
    float*       __restrict__ scales)
{
    const int wave = threadIdx.x >> 6;            // 0..3
    const int lane = threadIdx.x & 63;
    const int f    = blockIdx.x * 4 + wave;
    const int fm   = (blockIdx.x % (N_VFEAT / 4)) * 4 + wave;   // f % 768

    const float* a = W_ft  + (size_t)f  * FT_OUT;
    const float* g = W_fft + (size_t)fm * FT_OUT;

    float c[16];
#pragma unroll
    for (int ch = 0; ch < 4; ++ch) {
        const f4 av = __builtin_nontemporal_load(
            reinterpret_cast<const f4*>(a + ch * 256 + lane * 4));
        const f4 gv = *reinterpret_cast<const f4*>(g + ch * 256 + lane * 4);
        c[ch * 4 + 0] = av.x + gv.x;
        c[ch * 4 + 1] = av.y + gv.y;
        c[ch * 4 + 2] = av.z + gv.z;
        c[ch * 4 + 3] = av.w + gv.w;
    }

    float m = 0.0f;
#pragma unroll
    for (int j = 0; j < 16; ++j) m = fmaxf(m, fabsf(c[j]));
#pragma unroll
    for (int o = 32; o > 0; o >>= 1)
        m = fmaxf(m, __shfl_xor(m, o, 64));      // all lanes hold row max

    const float am  = fmaxf(m, 1e-20f);
    const float inv = 127.0f / am;
    if (lane == 0) scales[f] = am / 127.0f;

#pragma unroll
    for (int ch = 0; ch < 4; ++ch) {
        int q0 = (int)rintf(c[ch * 4 + 0] * inv);
        int q1 = (int)rintf(c[ch * 4 + 1] * inv);
        int q2 = (int)rintf(c[ch * 4 + 2] * inv);
        int q3 = (int)rintf(c[ch * 4 + 3] * inv);
        q0 = max(-127, min(127, q0)) + 128;
        q1 = max(-127, min(127, q1)) + 128;
        q2 = max(-127, min(127, q2)) + 128;
        q3 = max(-127, min(127, q3)) + 128;
        uchar4 pk;
        pk.x = (unsigned char)q0; pk.y = (unsigned char)q1;
        pk.z = (unsigned char)q2; pk.w = (unsigned char)q3;
        *reinterpret_cast<uchar4*>(Wq + (size_t)f * FT_OUT + ch * 256 + lane * 4) = pk;
    }
}

// ---------- main gather kernel: integer dot2 inner loop, deep MLP ----------
// 2 batch rows per 256-thread block; one WAVE per (batch, side); 16 cols/lane.
// unroll 8 => 16 16B-loads in flight per wave (~2x outstanding vs unroll 4),
// probing the latency-bound hypothesis for the HBM-miss fraction.
__global__ __launch_bounds__(256) void nnue_fwd_i8(
    const float*         __restrict__ values,
    const int*           __restrict__ stm_feat,
    const int*           __restrict__ nstm_feat,
    const unsigned char* __restrict__ Wq,
    const float*         __restrict__ scales,
    const float*         __restrict__ b_ft,
    const float*         __restrict__ b_fft,
    const float*         __restrict__ W_out,
    const float*         __restrict__ b_out,
    float*               __restrict__ out)
{
    const int tid  = threadIdx.x;
    const int wave = tid >> 6;          // 0..3
    const int lane = tid & 63;
    const int bl   = wave >> 1;         // batch slot within block (0..1)
    const int sd   = wave & 1;          // 0 = stm, 1 = nstm
    const int c0   = lane * 16;

    __shared__ int   s_off [2][2][FPP];      // row elem offsets
    __shared__ int   s_tp  [2][2][FPP / 2];  // packed {t_2k, t_2k+1} as i16x2
    __shared__ float s_sig [2][2];           // sigma = vmax/32767
    __shared__ int   s_tsum[2][2];           // SUM t_k
    __shared__ float s_red [2][2];

    if (tid < 128) {
        const int g  = tid >> 5;                       // (batch,side) group 0..3
        const int lb = g >> 1;
        const int ls = g & 1;
        const int k  = tid & 31;
        const int b  = blockIdx.x * 2 + lb;
        const int f  = (ls ? nstm_feat : stm_feat)[b * FPP + k];
        s_off[lb][ls][k] = f * FT_OUT;
        const float vs = values[b * FPP + k] * scales[f];

        float vmax = fabsf(vs);
#pragma unroll
        for (int o = 16; o > 0; o >>= 1)
            vmax = fmaxf(vmax, __shfl_xor(vmax, o, 32));
        vmax = fmaxf(vmax, 1e-30f);

        const int t = (int)rintf(vs * (32767.0f / vmax));
        int tsum = t;
#pragma unroll
        for (int o = 16; o > 0; o >>= 1)
            tsum += __shfl_xor(tsum, o, 32);
        const int tnext = __shfl_down(t, 1, 32);
        if ((k & 1) == 0)
            s_tp[lb][ls][k >> 1] = (t & 0xffff) | (tnext << 16);
        if (k == 0) {
            s_sig [lb][ls] = vmax / 32767.0f;
            s_tsum[lb][ls] = tsum;
        }
    }
    __syncthreads();

    int acci[16];
#pragma unroll
    for (int j = 0; j < 16; ++j) acci[j] = 0;

    // sel for byte j: {0x0C(=0), j(from S1=qb), 0x0C(=0), 4+j(from S0=qa)}
    //   -> dword { hi16 = u_b (row 2k+1), lo16 = u_a (row 2k) }, zero-extended.
#define DOT_STEP(d, av, bv)                                                          \
    acci[4*(d)+0] = sdot2(tp, (int)__builtin_amdgcn_perm((av), (bv), 0x0C000C04u), acci[4*(d)+0]); \
    acci[4*(d)+1] = sdot2(tp, (int)__builtin_amdgcn_perm((av), (bv), 0x0C010C05u), acci[4*(d)+1]); \
    acci[4*(d)+2] = sdot2(tp, (int)__builtin_amdgcn_perm((av), (bv), 0x0C020C06u), acci[4*(d)+2]); \
    acci[4*(d)+3] = sdot2(tp, (int)__builtin_amdgcn_perm((av), (bv), 0x0C030C07u), acci[4*(d)+3]);

#pragma unroll 8
    for (int kp = 0; kp < FPP / 2; ++kp) {
        const uint4 qa = *reinterpret_cast<const uint4*>(Wq + s_off[bl][sd][2 * kp]     + c0);
        const uint4 qb = *reinterpret_cast<const uint4*>(Wq + s_off[bl][sd][2 * kp + 1] + c0);
        const int tp = s_tp[bl][sd][kp];
        DOT_STEP(0, qa.x, qb.x)
        DOT_STEP(1, qa.y, qb.y)
        DOT_STEP(2, qa.z, qb.z)
        DOT_STEP(3, qa.w, qb.w)
    }
#undef DOT_STEP

    const float sigma = s_sig [bl][sd];
    const int   tsum  = s_tsum[bl][sd];
    const int   corr  = 128 * tsum;

    float partial = 0.0f;
#pragma unroll
    for (int ch = 0; ch < 4; ++ch) {
        const float4 bf = *reinterpret_cast<const float4*>(b_ft  + c0 + 4 * ch);
        const float4 bg = *reinterpret_cast<const float4*>(b_fft + c0 + 4 * ch);
        const float4 wo = *reinterpret_cast<const float4*>(W_out + sd * FT_OUT + c0 + 4 * ch);
        float h;
        h = sigma * (float)(acci[ch * 4 + 0] - corr) + bf.x + bg.x;
        h = fminf(fmaxf(h, 0.0f), 1.0f); partial += h * wo.x;
        h = sigma * (float)(acci[ch * 4 + 1] - corr) + bf.y + bg.y;
        h = fminf(fmaxf(h, 0.0f), 1.0f); partial += h * wo.y;
        h = sigma * (float)(acci[ch * 4 + 2] - corr) + bf.z + bg.z;
        h = fminf(fmaxf(h, 0.0f), 1.0f); partial += h * wo.z;
        h = sigma * (float)(acci[ch * 4 + 3] - corr) + bf.w + bg.w;
        h = fminf(fmaxf(h, 0.0f), 1.0f); partial += h * wo.w;
    }

#pragma unroll
    for (int o = 32; o > 0; o >>= 1)
        partial += __shfl_down(partial, o, 64);

    if (lane == 0) s_red[bl][sd] = partial;
    __syncthreads();

    if (tid < 2) {
        float x = s_red[tid][0] + s_red[tid][1] + b_out[0];
        out[blockIdx.x * 2 + tid] = 1.0f / (1.0f + __expf(-x));
    }
}

// ---------- fp32 fallback (used only if ws_size too small) ----------
__global__ __launch_bounds__(256) void nnue_fwd_f32(
    const float* __restrict__ values,
    const int*   __restrict__ stm_feat,
    const int*   __restrict__ nstm_feat,
    const float* __restrict__ W_ft,
    const float* __restrict__ b_ft,
    const float* __restrict__ W_fft,
    const float* __restrict__ b_fft,
    const float* __restrict__ W_out,
    const float* __restrict__ b_out,
    float*       __restrict__ out)
{
    const int b    = blockIdx.x;
    const int tid  = threadIdx.x;
    const int side = tid >> 7;
    const int lane = tid & 127;
    const int c0   = lane * 8;

    __shared__ int   s_off_ft [2][FPP];
    __shared__ int   s_off_fft[2][FPP];
    __shared__ float s_val[FPP];
    __shared__ float s_red[4];

    if (tid < FPP) {
        int f = stm_feat[b * FPP + tid];
        s_off_ft [0][tid] = f * FT_OUT;
        s_off_fft[0][tid] = (f % N_VFEAT) * FT_OUT;
        s_val[tid] = values[b * FPP + tid];
    } else if (tid < 2 * FPP) {
        int k = tid - FPP;
        int f = nstm_feat[b * FPP + k];
        s_off_ft [1][k] = f * FT_OUT;
        s_off_fft[1][k] = (f % N_VFEAT) * FT_OUT;
    }
    __syncthreads();

    float acc[8];
#pragma unroll
    for (int j = 0; j < 8; ++j) acc[j] = 0.0f;

#pragma unroll 4
    for (int k = 0; k < FPP; ++k) {
        const float* ra = W_ft  + s_off_ft [side][k] + c0;
        const float* rg = W_fft + s_off_fft[side][k] + c0;
        const float4 a0 = *reinterpret_cast<const float4*>(ra);
        const float4 a1 = *reinterpret_cast<const float4*>(ra + 4);
        const float4 g0 = *reinterpret_cast<const float4*>(rg);
        const float4 g1 = *reinterpret_cast<const float4*>(rg + 4);
        const float v = s_val[k];
        acc[0] += (a0.x + g0.x) * v;  acc[1] += (a0.y + g0.y) * v;
        acc[2] += (a0.z + g0.z) * v;  acc[3] += (a0.w + g0.w) * v;
        acc[4] += (a1.x + g1.x) * v;  acc[5] += (a1.y + g1.y) * v;
        acc[6] += (a1.z + g1.z) * v;  acc[7] += (a1.w + g1.w) * v;
    }

    float partial = 0.0f;
#pragma unroll
    for (int j = 0; j < 8; ++j) {
        float h = acc[j] + b_ft[c0 + j] + b_fft[c0 + j];
        h = fminf(fmaxf(h, 0.0f), 1.0f);
        partial += h * W_out[side * FT_OUT + c0 + j];
    }
#pragma unroll
    for (int o = 32; o > 0; o >>= 1)
        partial += __shfl_down(partial, o, 64);
    const int wv = tid >> 6;
    if ((tid & 63) == 0) s_red[wv] = partial;
    __syncthreads();
    if (tid == 0) {
        float x = s_red[0] + s_red[1] + s_red[2] + s_red[3] + b_out[0];
        out[b] = 1.0f / (1.0f + __expf(-x));
    }
}

extern "C" void kernel_launch(void* const* d_in, const int* in_sizes, int n_in,
                              void* d_out, int out_size, void* d_ws, size_t ws_size,
                              hipStream_t stream) {
    const float* values    = (const float*)d_in[0];
    const int*   stm_feat  = (const int*)d_in[1];
    const int*   nstm_feat = (const int*)d_in[2];
    // d_in[3] = batch_idx: structurally repeat(arange(B), FPP) -> nnz n maps to batch n>>5
    const float* W_ft      = (const float*)d_in[4];
    const float* b_ft      = (const float*)d_in[5];
    const float* W_fft     = (const float*)d_in[6];
    const float* b_fft     = (const float*)d_in[7];
    const float* W_out     = (const float*)d_in[8];
    const float* b_out     = (const float*)d_in[9];
    float*       out       = (float*)d_out;

    if (ws_size >= WS_NEEDED) {
        unsigned char* Wq     = (unsigned char*)d_ws;
        float*         scales = (float*)((char*)d_ws + WQ_BYTES);

        build_combined_i8<<<N_FEAT / 4, 256, 0, stream>>>(W_ft, W_fft, Wq, scales);

        nnue_fwd_i8<<<BATCH / 2, 256, 0, stream>>>(
            values, stm_feat, nstm_feat, Wq, scales, b_ft, b_fft, W_out, b_out, out);
    } else {
        nnue_fwd_f32<<<BATCH, 256, 0, stream>>>(
            values, stm_feat, nstm_feat, W_ft, b_ft, W_fft, b_fft, W_out, b_out, out);
    }
}